// Round 8
// baseline (259.365 us; speedup 1.0000x reference)
//
#include <hip/hip_runtime.h>

typedef __attribute__((ext_vector_type(8))) _Float16 half8;
typedef __attribute__((ext_vector_type(4))) float f32x4;
typedef unsigned short u16;

// ---------- fp16 helpers ----------
__device__ __forceinline__ u16 f2h(float x) {
    return __builtin_bit_cast(u16, (_Float16)x);   // RNE
}

// ---------- async global->LDS (16B/lane, linear dest: base + lane*16) ----------
__device__ __forceinline__ void g2l16(const u16* g, u16* l) {
    __builtin_amdgcn_global_load_lds(
        (const __attribute__((address_space(1))) void*)g,
        (__attribute__((address_space(3))) void*)l, 16, 0, 0);
}

// ---------- epilogue store dispatch ----------
__device__ __forceinline__ void storeC(float* C, size_t i, float v) { C[i] = v; }
__device__ __forceinline__ void storeC(u16* C, size_t i, float v)   { C[i] = f2h(v); }

// ---------- mask dtype detection (uint8 bool vs int32) ----------
__global__ void detect_mask_kernel(const unsigned char* __restrict__ m, int* __restrict__ flag) {
    __shared__ int any;
    if (threadIdx.x == 0) any = 0;
    __syncthreads();
    int base = threadIdx.x * 16;
    int local = 0;
#pragma unroll
    for (int j = 0; j < 16; ++j) {
        int idx = base + j;
        if ((idx & 3) != 0 && m[idx] != 0) local = 1;
    }
    if (local) atomicOr(&any, 1);
    __syncthreads();
    if (threadIdx.x == 0) flag[0] = any;
}

// ---------- cast fp32 -> f16 (+ optional copy into cat right half) ----------
__global__ __launch_bounds__(256) void cast_f16_kernel(
    const float* __restrict__ x, u16* __restrict__ dst,
    u16* __restrict__ cat_right, long n)
{
    long i = ((long)blockIdx.x * 256 + threadIdx.x) * 4;
    if (i >= n) return;
    const float4 v = *(const float4*)(x + i);
    ushort4 h = make_ushort4(f2h(v.x), f2h(v.y), f2h(v.z), f2h(v.w));
    *(ushort4*)(dst + i) = h;
    if (cat_right) {
        long row = i >> 10, col = i & 1023;     // D = 1024
        *(ushort4*)(cat_right + row * 2048 + col) = h;
    }
}

// ---------- fused enc cast+transpose: fp32 [b][2048][1024] -> f16 [k][d] AND f16 [d][k] ----------
__global__ __launch_bounds__(256) void cast_enc_kernel(
    const float* __restrict__ src, u16* __restrict__ enc16, u16* __restrict__ encT)
{
    __shared__ u16 tile[64][68];
    const int b  = blockIdx.z;
    const int k0 = blockIdx.x * 64;
    const int d0 = blockIdx.y * 64;
    const int t  = threadIdx.x;
    const int kr = t >> 4;            // 0..15
    const int dc = (t & 15) * 4;      // 0..60
#pragma unroll
    for (int i = 0; i < 4; ++i) {
        const int k = kr + i * 16;
        const size_t off = ((size_t)(b * 2048 + k0 + k)) * 1024 + d0 + dc;
        const float4 v = *(const float4*)(src + off);
        const u16 h0 = f2h(v.x), h1 = f2h(v.y), h2 = f2h(v.z), h3 = f2h(v.w);
        *(ushort4*)(enc16 + off) = make_ushort4(h0, h1, h2, h3);
        tile[k][dc] = h0; tile[k][dc + 1] = h1; tile[k][dc + 2] = h2; tile[k][dc + 3] = h3;
    }
    __syncthreads();
#pragma unroll
    for (int i = 0; i < 4; ++i) {
        const int d = kr + i * 16;
        ushort4 o = make_ushort4(tile[dc][d], tile[dc + 1][d], tile[dc + 2][d], tile[dc + 3][d]);
        *(ushort4*)(encT + ((size_t)(b * 1024 + d0 + d)) * 2048 + k0 + dc) = o;
    }
}

// ---------- 4-wave pipelined GEMM: C[M][N] = A[M][K] * B[N][K]^T (f16, k-contiguous) ----------
// BM=BN=128, BK=32. 4 waves (2M x 2N), per-wave 64x64 output, 32KB LDS double-buffer
// -> 3 blocks/CU co-resident (independent barrier domains hide each other's stalls).
// T2 XOR chunk swizzle (4 chunks/row), T4 counted vmcnt(4), T5 setprio, T1 XCD swizzle.
template<typename CT>
__global__ __launch_bounds__(256, 3) void gemm4_kernel(
    const u16* __restrict__ A, int lda, long sAb,
    const u16* __restrict__ B, int ldb, long sBb,
    CT* __restrict__ C, int ldc, long sCb,
    int K, int nmt, int nnt)
{
    constexpr int AE = 128 * 32;         // 4096 elems per tile (8KB)
    __shared__ u16 smem[4 * AE];         // 2 buffers x (A+B) = 32KB

    const int t = threadIdx.x;
    const int lane = t & 63, wid = t >> 6;      // 4 waves
    const int wr = wid >> 1, wc = wid & 1;
    const int lr = lane & 15, lh = lane >> 4;   // lh: k-chunk 0..3

    // T1: XCD swizzle (gridDim multiple of 8, bijective)
    const int bid = blockIdx.x;
    const int swz = (bid & 7) * ((int)gridDim.x >> 3) + (bid >> 3);
    const int per_b = nmt * nnt;
    const int b   = swz / per_b;
    const int rem = swz % per_b;
    const long row0 = (long)(rem / nnt) * 128;
    const long col0 = (long)(rem % nnt) * 128;

    A += (size_t)b * sAb;
    B += (size_t)b * sBb;
    C += (size_t)b * sCb;

    // staging: per wave 2 calls A + 2 calls B, 16 rows/call (64 lanes x 8 elems, 32/row).
    // source chunk pre-swizzled: slot j of row R holds source chunk j^(R&3).
    const int srow = lane >> 2;                        // 0..15
    const int scol = ((lane & 3) ^ (srow & 3)) * 8;    // element offset in BK=32
    const u16* pa[2];
    const u16* pb[2];
#pragma unroll
    for (int c = 0; c < 2; ++c) {
        pa[c] = A + (size_t)(row0 + wid * 32 + c * 16 + srow) * lda + scol;
        pb[c] = B + (size_t)(col0 + wid * 32 + c * 16 + srow) * ldb + scol;
    }

    f32x4 acc[4][4] = {};

    const int NT = K / 32;

    auto stage = [&](long ko, int buf) {
        u16* sAn = smem + buf * 2 * AE;
        u16* sBn = sAn + AE;
#pragma unroll
        for (int c = 0; c < 2; ++c) g2l16(pa[c] + ko, sAn + wid * 1024 + c * 512);
#pragma unroll
        for (int c = 0; c < 2; ++c) g2l16(pb[c] + ko, sBn + wid * 1024 + c * 512);
    };

    stage(0, 0);   // prologue: tile 0 -> buf 0

    int cur = 0;
    for (int tt = 0; tt < NT; ++tt) {
        if (tt + 1 < NT) {
            stage((long)(tt + 1) * 32, cur ^ 1);
            // counted wait: tile tt's 4 loads (oldest) land; tile tt+1's 4 stay in flight
            asm volatile("s_waitcnt vmcnt(4)" ::: "memory");
        } else {
            asm volatile("s_waitcnt vmcnt(0)" ::: "memory");
        }
        __builtin_amdgcn_s_barrier();

        const u16* sAc = smem + cur * 2 * AE;
        const u16* sBc = sAc + AE;

        half8 Ar[4], Br[4];
        // read-side swizzle: row r, k-chunk lh lives at slot lh^(r&3)
#pragma unroll
        for (int fi = 0; fi < 4; ++fi) {
            const int r = wr * 64 + fi * 16 + lr;
            Ar[fi] = *(const half8*)&sAc[r * 32 + ((lh ^ (r & 3)) * 8)];
        }
#pragma unroll
        for (int fj = 0; fj < 4; ++fj) {
            const int r = wc * 64 + fj * 16 + lr;
            Br[fj] = *(const half8*)&sBc[r * 32 + ((lh ^ (r & 3)) * 8)];
        }

        __builtin_amdgcn_s_setprio(1);
#pragma unroll
        for (int fi = 0; fi < 4; ++fi)
#pragma unroll
            for (int fj = 0; fj < 4; ++fj)
                acc[fi][fj] = __builtin_amdgcn_mfma_f32_16x16x32_f16(
                    Ar[fi], Br[fj], acc[fi][fj], 0, 0, 0);
        __builtin_amdgcn_s_setprio(0);

        __builtin_amdgcn_s_barrier();
        cur ^= 1;
    }

    // epilogue: C/D mapping col = lane&15, row = (lane>>4)*4 + reg
#pragma unroll
    for (int fi = 0; fi < 4; ++fi) {
        const long rb = row0 + wr * 64 + fi * 16 + lh * 4;
#pragma unroll
        for (int fj = 0; fj < 4; ++fj) {
            const long c = col0 + wc * 64 + fj * 16 + lr;
#pragma unroll
            for (int r = 0; r < 4; ++r)
                storeC(C, (size_t)(rb + r) * ldc + c, acc[fi][fj][r]);
        }
    }
}

// ---------- row softmax WITH mask: scores f16 [8192][2048] (+mask) -> P f16 ----------
__global__ __launch_bounds__(256) void softmax_kernel(
    const u16* __restrict__ S, const unsigned char* __restrict__ mask8,
    const int* __restrict__ mask32, const int* __restrict__ mflagp,
    u16* __restrict__ P)
{
    const long row = blockIdx.x;
    const int t = threadIdx.x;
    const int lane = t & 63, wid = t >> 6;
    const int mf = *mflagp;   // 1 -> uint8 bool, 0 -> int32
    const half8 a = *(const half8*)(S + row * 2048 + t * 8);
    float v[8];
#pragma unroll
    for (int i = 0; i < 8; ++i) v[i] = (float)a[i];

    // coalesced mask read + apply
    const float NINF = -__builtin_inff();
    if (mf) {
        const unsigned long long mm =
            *(const unsigned long long*)(mask8 + row * 2048 + t * 8);
#pragma unroll
        for (int i = 0; i < 8; ++i)
            if ((mm >> (8 * i)) & 0xffULL) v[i] = NINF;
    } else {
        const int4 ma = *(const int4*)(mask32 + row * 2048 + t * 8);
        const int4 mb = *(const int4*)(mask32 + row * 2048 + t * 8 + 4);
        if (ma.x) v[0] = NINF; if (ma.y) v[1] = NINF;
        if (ma.z) v[2] = NINF; if (ma.w) v[3] = NINF;
        if (mb.x) v[4] = NINF; if (mb.y) v[5] = NINF;
        if (mb.z) v[6] = NINF; if (mb.w) v[7] = NINF;
    }

    float m = v[0];
#pragma unroll
    for (int i = 1; i < 8; ++i) m = fmaxf(m, v[i]);
#pragma unroll
    for (int off = 32; off; off >>= 1) m = fmaxf(m, __shfl_xor(m, off));
    __shared__ float redm[4];
    __shared__ float reds[4];
    if (lane == 0) redm[wid] = m;
    __syncthreads();
    m = fmaxf(fmaxf(redm[0], redm[1]), fmaxf(redm[2], redm[3]));

    float e[8], s = 0.f;
#pragma unroll
    for (int i = 0; i < 8; ++i) { e[i] = __expf(v[i] - m); s += e[i]; }
#pragma unroll
    for (int off = 32; off; off >>= 1) s += __shfl_xor(s, off);
    if (lane == 0) reds[wid] = s;
    __syncthreads();
    s = (reds[0] + reds[1]) + (reds[2] + reds[3]);
    const float inv = 1.0f / s;

    ushort4 o0, o1;
    o0 = make_ushort4(f2h(e[0] * inv), f2h(e[1] * inv), f2h(e[2] * inv), f2h(e[3] * inv));
    o1 = make_ushort4(f2h(e[4] * inv), f2h(e[5] * inv), f2h(e[6] * inv), f2h(e[7] * inv));
    *(ushort4*)(P + row * 2048 + t * 8)     = o0;
    *(ushort4*)(P + row * 2048 + t * 8 + 4) = o1;
}

// ---------- launch ----------
extern "C" void kernel_launch(void* const* d_in, const int* in_sizes, int n_in,
                              void* d_out, int out_size, void* d_ws, size_t ws_size,
                              hipStream_t stream)
{
    const float* dec  = (const float*)d_in[0];          // [16][512][1024]
    const float* enc  = (const float*)d_in[1];          // [16][2048][1024]
    const void*  mask = (const void*)d_in[2];           // [16][512][2048] bool or int32
    const float* W    = (const float*)d_in[3];          // [1024][2048]
    float* out        = (float*)d_out;                  // [16][512][1024]

    // workspace carve (total 255,856,640 B)
    char* ws = (char*)d_ws;
    u16*   dec16    = (u16*)ws;               ws += 16777216;   // 8192x1024 f16
    u16*   enc16    = (u16*)ws;               ws += 67108864;   // 16x2048x1024 f16
    u16*   encT     = (u16*)ws;               ws += 67108864;   // 16x1024x2048 f16
    u16*   W16      = (u16*)ws;               ws += 4194304;    // 1024x2048 f16
    u16*   scores16 = (u16*)ws;               ws += 33554432;   // 8192x2048 f16
    u16*   P        = (u16*)ws;               ws += 33554432;   // 8192x2048 f16
    u16*   cat      = (u16*)ws;               ws += 33554432;   // 8192x2048 f16
    int*   mflag    = (int*)ws;               ws += 4096;       // mask dtype flag
    if (ws_size < (size_t)255856640) return;

    // 0) detect mask dtype (needed by softmax)
    detect_mask_kernel<<<1, 256, 0, stream>>>((const unsigned char*)mask, mflag);

    // 1) casts
    cast_f16_kernel<<<8192, 256, 0, stream>>>(dec, dec16, cat + 1024, 8388608L);
    cast_enc_kernel<<<dim3(32, 16, 16), 256, 0, stream>>>(enc, enc16, encT);
    cast_f16_kernel<<<2048, 256, 0, stream>>>(W, W16, nullptr, 2097152L);

    // 2) scores = dec @ enc^T -> f16  (128x128 tiles, 16b x 4 x 16 = 1024 blocks, 3/CU)
    gemm4_kernel<u16><<<1024, 256, 0, stream>>>(
        dec16, 1024, 512L * 1024,
        enc16, 1024, 2048L * 1024,
        scores16, 2048, 512L * 2048,
        1024, 4, 16);

    // 3) mask + softmax rows -> P (f16)
    softmax_kernel<<<8192, 256, 0, stream>>>(
        scores16, (const unsigned char*)mask, (const int*)mask, mflag, P);

    // 4) context = P @ encT^T -> cat left half  (16b x 4 x 8 = 512 blocks)
    gemm4_kernel<u16><<<512, 256, 0, stream>>>(
        P, 2048, 512L * 2048,
        encT, 2048, 1024L * 2048,
        cat, 2048, 512L * 2048,
        2048, 4, 8);

    // 5) out = cat @ W^T -> fp32  (64 x 8 = 512 blocks, batch-free)
    gemm4_kernel<float><<<512, 256, 0, stream>>>(
        cat, 2048, 0,
        W16, 2048, 0,
        out, 1024, 0,
        2048, 64, 8);
}

// Round 9
// 227.372 us; speedup vs baseline: 1.1407x; 1.1407x over previous
//
#include <hip/hip_runtime.h>

typedef __attribute__((ext_vector_type(8))) _Float16 half8;
typedef __attribute__((ext_vector_type(4))) float f32x4;
typedef unsigned short u16;

// ---------- fp16 helpers ----------
__device__ __forceinline__ u16 f2h(float x) {
    return __builtin_bit_cast(u16, (_Float16)x);   // RNE
}

// ---------- async global->LDS (16B/lane, linear dest: base + lane*16) ----------
__device__ __forceinline__ void g2l16(const u16* g, u16* l) {
    __builtin_amdgcn_global_load_lds(
        (const __attribute__((address_space(1))) void*)g,
        (__attribute__((address_space(3))) void*)l, 16, 0, 0);
}

// ---------- epilogue store dispatch ----------
__device__ __forceinline__ void storeC(float* C, size_t i, float v) { C[i] = v; }
__device__ __forceinline__ void storeC(u16* C, size_t i, float v)   { C[i] = f2h(v); }

// ---------- mask dtype detection (uint8 bool vs int32) ----------
__global__ void detect_mask_kernel(const unsigned char* __restrict__ m, int* __restrict__ flag) {
    __shared__ int any;
    if (threadIdx.x == 0) any = 0;
    __syncthreads();
    int base = threadIdx.x * 16;
    int local = 0;
#pragma unroll
    for (int j = 0; j < 16; ++j) {
        int idx = base + j;
        if ((idx & 3) != 0 && m[idx] != 0) local = 1;
    }
    if (local) atomicOr(&any, 1);
    __syncthreads();
    if (threadIdx.x == 0) flag[0] = any;
}

// ---------- cast fp32 -> f16 ----------
__global__ __launch_bounds__(256) void cast_f16_kernel(
    const float* __restrict__ x, u16* __restrict__ dst, long n)
{
    long i = ((long)blockIdx.x * 256 + threadIdx.x) * 4;
    if (i >= n) return;
    const float4 v = *(const float4*)(x + i);
    *(ushort4*)(dst + i) = make_ushort4(f2h(v.x), f2h(v.y), f2h(v.z), f2h(v.w));
}

// ---------- fused enc cast+transpose: fp32 [b][2048][1024] -> f16 [k][d] AND f16 [d][k] ----------
__global__ __launch_bounds__(256) void cast_enc_kernel(
    const float* __restrict__ src, u16* __restrict__ enc16, u16* __restrict__ encT)
{
    __shared__ u16 tile[64][68];
    const int b  = blockIdx.z;
    const int k0 = blockIdx.x * 64;
    const int d0 = blockIdx.y * 64;
    const int t  = threadIdx.x;
    const int kr = t >> 4;            // 0..15
    const int dc = (t & 15) * 4;      // 0..60
#pragma unroll
    for (int i = 0; i < 4; ++i) {
        const int k = kr + i * 16;
        const size_t off = ((size_t)(b * 2048 + k0 + k)) * 1024 + d0 + dc;
        const float4 v = *(const float4*)(src + off);
        const u16 h0 = f2h(v.x), h1 = f2h(v.y), h2 = f2h(v.z), h3 = f2h(v.w);
        *(ushort4*)(enc16 + off) = make_ushort4(h0, h1, h2, h3);
        tile[k][dc] = h0; tile[k][dc + 1] = h1; tile[k][dc + 2] = h2; tile[k][dc + 3] = h3;
    }
    __syncthreads();
#pragma unroll
    for (int i = 0; i < 4; ++i) {
        const int d = kr + i * 16;
        ushort4 o = make_ushort4(tile[dc][d], tile[dc + 1][d], tile[dc + 2][d], tile[dc + 3][d]);
        *(ushort4*)(encT + ((size_t)(b * 1024 + d0 + d)) * 2048 + k0 + dc) = o;
    }
}

// ---------- 8-wave phased GEMM: C[M][N] = A[M][K] * B[N][K]^T (f16, k-contiguous) ----------
// BM=256, BN=128, BK=64. 8 waves (2M x 4N), per-wave 128x32 output.
// TRIPLE-buffered LDS (144KB), depth-2 prefetch; staging spread INSIDE phases (m201 port):
// per iter: 2 phases x {ds_read subtile, 3 g2l16 for tile tt+2, barrier, lgkmcnt(0),
// setprio(1) 16 MFMA setprio(0), barrier}; single counted vmcnt(6) at iter bottom.
// SPLIT: A-source switches at k=1024 from A(ctx) to A2(dec16), both lda=1024.
template<bool SPLIT, typename CT>
__global__ __launch_bounds__(512, 2) void gemm8_kernel(
    const u16* __restrict__ A, const u16* __restrict__ A2, int lda, long sAb,
    const u16* __restrict__ B, int ldb, long sBb,
    CT* __restrict__ C, int ldc, long sCb,
    int K, int nmt, int nnt)
{
    constexpr int AE = 256 * 64;         // 16384 elems (32KB)
    constexpr int BE = 128 * 64;         // 8192 elems (16KB)
    __shared__ u16 smem[3 * (AE + BE)];  // 144KB triple buffer

    const int t = threadIdx.x;
    const int lane = t & 63, wid = t >> 6;
    const int wr = wid >> 2, wc = wid & 3;
    const int lr = lane & 15, lh = lane >> 4;

    // T1: XCD swizzle (gridDim multiple of 8, bijective)
    const int bid = blockIdx.x;
    const int swz = (bid & 7) * ((int)gridDim.x >> 3) + (bid >> 3);
    const int per_b = nmt * nnt;
    const int b   = swz / per_b;
    const int rem = swz % per_b;
    const long row0 = (long)(rem / nnt) * 256;
    const long col0 = (long)(rem % nnt) * 128;

    A += (size_t)b * sAb;
    B += (size_t)b * sBb;
    C += (size_t)b * sCb;

    // staging geometry: 8 rows/call/wave; source chunk pre-swizzled (involution)
    const int srow = lane >> 3;                       // 0..7
    const int scol = ((lane & 7) ^ (lane >> 3)) * 8;  // element offset in BK=64
    size_t oa[4]; const u16* pb[2];
#pragma unroll
    for (int c = 0; c < 4; ++c)
        oa[c] = (size_t)(row0 + wid * 32 + c * 8 + srow) * lda + scol;
#pragma unroll
    for (int c = 0; c < 2; ++c)
        pb[c] = B + (size_t)(col0 + wid * 16 + c * 8 + srow) * ldb + scol;

    f32x4 acc[8][2] = {};

    // read-side swizzled chunk terms: ((ks*4+lh) ^ (lr&7)) * 8
    const int ch0 = ((0 * 4 + lh) ^ (lr & 7)) * 8;
    const int ch1 = ((1 * 4 + lh) ^ (lr & 7)) * 8;

    const int NT = K / 64;

    auto aptr = [&](int c, long ko) -> const u16* {
        if constexpr (SPLIT)
            return (ko < 1024 ? A : A2) + oa[c] + (ko & 1023);
        else
            return A + oa[c] + ko;
    };
    // part 0: A calls 0,1 + B call 0 ; part 1: A calls 2,3 + B call 1
    auto stage_part = [&](int tile, int buf, int part) {
        const long ko = (long)tile * 64;
        u16* sAn = smem + buf * (AE + BE);
        u16* sBn = sAn + AE;
        const int c0 = part * 2;
        g2l16(aptr(c0,     ko), sAn + wid * 2048 + c0 * 512);
        g2l16(aptr(c0 + 1, ko), sAn + wid * 2048 + c0 * 512 + 512);
        g2l16(pb[part] + ko,    sBn + wid * 1024 + part * 512);
    };

    // prologue: tiles 0,1 -> bufs 0,1; wait tile 0 (keep tile 1's 6 in flight)
    stage_part(0, 0, 0); stage_part(0, 0, 1);
    stage_part(1, 1, 0); stage_part(1, 1, 1);
    asm volatile("s_waitcnt vmcnt(6)" ::: "memory");
    __builtin_amdgcn_s_barrier();

    int cb = 0, sb = 2;
    for (int tt = 0; tt < NT; ++tt) {
        const u16* sAc = smem + cb * (AE + BE);
        const u16* sBc = sAc + AE;
        const bool st = (tt + 2 < NT);

        half8 Ar[4][2], Bq0[2], Bq1[2];

        auto ldA = [&](int mh) {
#pragma unroll
            for (int fi = 0; fi < 4; ++fi) {
                const int r = wr * 128 + (mh * 4 + fi) * 16 + lr;
                Ar[fi][0] = *(const half8*)&sAc[r * 64 + ch0];
                Ar[fi][1] = *(const half8*)&sAc[r * 64 + ch1];
            }
        };
        auto ldB = [&](half8 (&Br)[2], int nh) {
            const int r = wc * 32 + nh * 16 + lr;
            Br[0] = *(const half8*)&sBc[r * 64 + ch0];
            Br[1] = *(const half8*)&sBc[r * 64 + ch1];
        };
        auto quad = [&](half8 (&Br)[2], int mh, int nh) {
#pragma unroll
            for (int fi = 0; fi < 4; ++fi)
#pragma unroll
                for (int ks = 0; ks < 2; ++ks)
                    acc[mh * 4 + fi][nh] = __builtin_amdgcn_mfma_f32_16x16x32_f16(
                        Ar[fi][ks], Br[ks], acc[mh * 4 + fi][nh], 0, 0, 0);
        };

        // ---- Phase 1 ----
        ldA(0); ldB(Bq0, 0); ldB(Bq1, 1);        // 12 ds_read_b128
        if (st) stage_part(tt + 2, sb, 0);       // 3 g2l16 in flight across phases
        __builtin_amdgcn_s_barrier();
        asm volatile("s_waitcnt lgkmcnt(0)" ::: "memory");
        __builtin_amdgcn_s_setprio(1);
        quad(Bq0, 0, 0); quad(Bq1, 0, 1);        // 16 MFMA
        __builtin_amdgcn_s_setprio(0);
        __builtin_amdgcn_s_barrier();

        // ---- Phase 2 ----
        ldA(1);                                  // 8 ds_read_b128
        if (st) stage_part(tt + 2, sb, 1);
        __builtin_amdgcn_s_barrier();
        asm volatile("s_waitcnt lgkmcnt(0)" ::: "memory");
        __builtin_amdgcn_s_setprio(1);
        quad(Bq1, 1, 1); quad(Bq0, 1, 0);        // 16 MFMA
        __builtin_amdgcn_s_setprio(0);

        // iter-bottom counted wait: tile tt+1 fully resident for next iter;
        // tile tt+2's 6 loads stay in flight.
        if (st) asm volatile("s_waitcnt vmcnt(6)" ::: "memory");
        else    asm volatile("s_waitcnt vmcnt(0)" ::: "memory");
        __builtin_amdgcn_s_barrier();

        cb = (cb == 2) ? 0 : cb + 1;
        sb = (sb == 2) ? 0 : sb + 1;
    }

    // epilogue: C/D mapping col = lane&15, row = (lane>>4)*4 + reg
#pragma unroll
    for (int f = 0; f < 8; ++f) {
        const long rb = row0 + wr * 128 + f * 16 + lh * 4;
#pragma unroll
        for (int n = 0; n < 2; ++n) {
            const long c = col0 + wc * 32 + n * 16 + lr;
#pragma unroll
            for (int r = 0; r < 4; ++r)
                storeC(C, (size_t)(rb + r) * ldc + c, acc[f][n][r]);
        }
    }
}

// ---------- row softmax WITH mask: scores f16 [8192][2048] (+mask) -> P f16 ----------
__global__ __launch_bounds__(256) void softmax_kernel(
    const u16* __restrict__ S, const unsigned char* __restrict__ mask8,
    const int* __restrict__ mask32, const int* __restrict__ mflagp,
    u16* __restrict__ P)
{
    const long row = blockIdx.x;
    const int t = threadIdx.x;
    const int lane = t & 63, wid = t >> 6;
    const int mf = *mflagp;   // 1 -> uint8 bool, 0 -> int32
    const half8 a = *(const half8*)(S + row * 2048 + t * 8);
    float v[8];
#pragma unroll
    for (int i = 0; i < 8; ++i) v[i] = (float)a[i];

    const float NINF = -__builtin_inff();
    if (mf) {
        const unsigned long long mm =
            *(const unsigned long long*)(mask8 + row * 2048 + t * 8);
#pragma unroll
        for (int i = 0; i < 8; ++i)
            if ((mm >> (8 * i)) & 0xffULL) v[i] = NINF;
    } else {
        const int4 ma = *(const int4*)(mask32 + row * 2048 + t * 8);
        const int4 mb = *(const int4*)(mask32 + row * 2048 + t * 8 + 4);
        if (ma.x) v[0] = NINF; if (ma.y) v[1] = NINF;
        if (ma.z) v[2] = NINF; if (ma.w) v[3] = NINF;
        if (mb.x) v[4] = NINF; if (mb.y) v[5] = NINF;
        if (mb.z) v[6] = NINF; if (mb.w) v[7] = NINF;
    }

    float m = v[0];
#pragma unroll
    for (int i = 1; i < 8; ++i) m = fmaxf(m, v[i]);
#pragma unroll
    for (int off = 32; off; off >>= 1) m = fmaxf(m, __shfl_xor(m, off));
    __shared__ float redm[4];
    __shared__ float reds[4];
    if (lane == 0) redm[wid] = m;
    __syncthreads();
    m = fmaxf(fmaxf(redm[0], redm[1]), fmaxf(redm[2], redm[3]));

    float e[8], s = 0.f;
#pragma unroll
    for (int i = 0; i < 8; ++i) { e[i] = __expf(v[i] - m); s += e[i]; }
#pragma unroll
    for (int off = 32; off; off >>= 1) s += __shfl_xor(s, off);
    if (lane == 0) reds[wid] = s;
    __syncthreads();
    s = (reds[0] + reds[1]) + (reds[2] + reds[3]);
    const float inv = 1.0f / s;

    ushort4 o0 = make_ushort4(f2h(e[0]*inv), f2h(e[1]*inv), f2h(e[2]*inv), f2h(e[3]*inv));
    ushort4 o1 = make_ushort4(f2h(e[4]*inv), f2h(e[5]*inv), f2h(e[6]*inv), f2h(e[7]*inv));
    *(ushort4*)(P + row * 2048 + t * 8)     = o0;
    *(ushort4*)(P + row * 2048 + t * 8 + 4) = o1;
}

// ---------- launch ----------
extern "C" void kernel_launch(void* const* d_in, const int* in_sizes, int n_in,
                              void* d_out, int out_size, void* d_ws, size_t ws_size,
                              hipStream_t stream)
{
    const float* dec  = (const float*)d_in[0];          // [16][512][1024]
    const float* enc  = (const float*)d_in[1];          // [16][2048][1024]
    const void*  mask = (const void*)d_in[2];           // [16][512][2048] bool or int32
    const float* W    = (const float*)d_in[3];          // [1024][2048]
    float* out        = (float*)d_out;                  // [16][512][1024]

    // workspace carve (total 239,079,424 B)
    char* ws = (char*)d_ws;
    u16*   dec16    = (u16*)ws;               ws += 16777216;   // 8192x1024 f16
    u16*   enc16    = (u16*)ws;               ws += 67108864;   // 16x2048x1024 f16
    u16*   encT     = (u16*)ws;               ws += 67108864;   // 16x1024x2048 f16
    u16*   W16      = (u16*)ws;               ws += 4194304;    // 1024x2048 f16
    u16*   scores16 = (u16*)ws;               ws += 33554432;   // 8192x2048 f16
    u16*   P        = (u16*)ws;               ws += 33554432;   // 8192x2048 f16
    u16*   ctx      = (u16*)ws;               ws += 16777216;   // 8192x1024 f16
    int*   mflag    = (int*)ws;               ws += 4096;       // mask dtype flag
    if (ws_size < (size_t)239079424) return;

    // 0) detect mask dtype (needed by softmax)
    detect_mask_kernel<<<1, 256, 0, stream>>>((const unsigned char*)mask, mflag);

    // 1) casts
    cast_f16_kernel<<<8192, 256, 0, stream>>>(dec, dec16, 8388608L);
    cast_enc_kernel<<<dim3(32, 16, 16), 256, 0, stream>>>(enc, enc16, encT);
    cast_f16_kernel<<<2048, 256, 0, stream>>>(W, W16, 2097152L);

    // 2) scores = dec @ enc^T -> f16  (256x128 tiles, 16b x 2 x 16 = 512 blocks)
    gemm8_kernel<false, u16><<<512, 512, 0, stream>>>(
        dec16, nullptr, 1024, 512L * 1024,
        enc16, 1024, 2048L * 1024,
        scores16, 2048, 512L * 2048,
        1024, 2, 16);

    // 3) mask + softmax rows -> P (f16)
    softmax_kernel<<<8192, 256, 0, stream>>>(
        scores16, (const unsigned char*)mask, (const int*)mask, mflag, P);

    // 4) context = P @ encT^T -> ctx (flat [8192][1024])  (16b x 2 x 8 = 256 blocks)
    gemm8_kernel<false, u16><<<256, 512, 0, stream>>>(
        P, nullptr, 2048, 512L * 2048,
        encT, 2048, 1024L * 2048,
        ctx, 1024, 512L * 1024,
        2048, 2, 8);

    // 5) out = [ctx | dec16] @ W^T -> fp32  (A-split at k=1024; 32 x 8 = 256 blocks)
    gemm8_kernel<true, float><<<256, 512, 0, stream>>>(
        ctx, dec16, 1024, 0,
        W16, 2048, 0,
        out, 1024, 0,
        2048, 32, 8);
}